// Round 8
// baseline (463.288 us; speedup 1.0000x reference)
//
#include <hip/hip_runtime.h>

// ---------------------------------------------------------------------------
// UNet_old (graph U-Net, GMMConv K=10) on MI355X. fp32 in / fp32 out.
// R8: hoist Gaussian-weight computation out of all aggregation kernels.
// R7 post-mortem: aggf spends ~2.3G lane-ops, ~half of it the SAME 10 exp
// recomputed by each of TPN threads per edge (VALUBusy 48%, no spill —
// accumulators live in AGPRs; launch_bounds was a no-op). k_gw now computes
// gw per (layer, CSR slot) once (batched over 5 layer-graph pairs, fp32
// padded to 12 for aligned float4 loads); aggregation loops become pure
// fma + streams, freeing 40 const VGPRs each.
// ---------------------------------------------------------------------------

#define N0C 65536
#define N1C 8192
#define N2C 1024
#define KK 10

typedef _Float16 half4 __attribute__((ext_vector_type(4)));
typedef _Float16 f16x8 __attribute__((ext_vector_type(8)));
typedef float f32x4 __attribute__((ext_vector_type(4)));

static inline int cdiv(long long a, long long b) { return (int)((a + b - 1) / b); }

// ---------------- batched CSR build (3 graphs) ----------------

__global__ __launch_bounds__(256)
void k_hist3(const int* __restrict__ d1, const int* __restrict__ d2,
             const int* __restrict__ d3, int* __restrict__ g1,
             int* __restrict__ g2, int* __restrict__ g3,
             int E1, int E2, int E3) {
    int i = blockIdx.x * 256 + threadIdx.x;
    if (i < E1) atomicAdd(&g1[d1[i]], 1);
    else if (i < E1 + E2) atomicAdd(&g2[d2[i - E1]], 1);
    else if (i < E1 + E2 + E3) atomicAdd(&g3[d3[i - E1 - E2]], 1);
}

__device__ __forceinline__ void map_graph(int b, int& lb, int& gi) {
    if (b < 256) { gi = 0; lb = b; }
    else if (b < 288) { gi = 1; lb = b - 256; }
    else { gi = 2; lb = b - 288; }
}

__global__ __launch_bounds__(256)
void k_scan1_3(const int* __restrict__ deg1, int* __restrict__ off1,
               const int* __restrict__ deg2, int* __restrict__ off2,
               const int* __restrict__ deg3, int* __restrict__ off3,
               int* __restrict__ part) {
    __shared__ int s[256];
    int lb, gi; map_graph(blockIdx.x, lb, gi);
    const int* deg = gi == 0 ? deg1 : (gi == 1 ? deg2 : deg3);
    int* off = gi == 0 ? off1 : (gi == 1 ? off2 : off3);
    int* prt = part + (gi == 0 ? 0 : (gi == 1 ? 256 : 288));
    int i = lb * 256 + threadIdx.x;
    int v = deg[i];
    s[threadIdx.x] = v;
    __syncthreads();
#pragma unroll
    for (int d = 1; d < 256; d <<= 1) {
        int t = (threadIdx.x >= d) ? s[threadIdx.x - d] : 0;
        __syncthreads();
        s[threadIdx.x] += t;
        __syncthreads();
    }
    off[i] = s[threadIdx.x] - v;
    if (threadIdx.x == 255) prt[lb] = s[255];
}

__global__ __launch_bounds__(256)
void k_scan2_3(int* __restrict__ part) {
    __shared__ int s[256];
    int nb = blockIdx.x == 0 ? 256 : (blockIdx.x == 1 ? 32 : 4);
    int* p = part + (blockIdx.x == 0 ? 0 : (blockIdx.x == 1 ? 256 : 288));
    int v = (threadIdx.x < nb) ? p[threadIdx.x] : 0;
    s[threadIdx.x] = v;
    __syncthreads();
#pragma unroll
    for (int d = 1; d < 256; d <<= 1) {
        int t = (threadIdx.x >= d) ? s[threadIdx.x - d] : 0;
        __syncthreads();
        s[threadIdx.x] += t;
        __syncthreads();
    }
    if (threadIdx.x < nb) p[threadIdx.x] = s[threadIdx.x] - v;
}

__global__ __launch_bounds__(256)
void k_scan3_3(int* __restrict__ off1, int* __restrict__ off2, int* __restrict__ off3,
               const int* __restrict__ part,
               const int* __restrict__ deg1, const int* __restrict__ deg2,
               const int* __restrict__ deg3,
               float* __restrict__ inv1, float* __restrict__ inv2,
               float* __restrict__ inv3, int E1, int E2, int E3) {
    int lb, gi; map_graph(blockIdx.x, lb, gi);
    int* off = gi == 0 ? off1 : (gi == 1 ? off2 : off3);
    const int* deg = gi == 0 ? deg1 : (gi == 1 ? deg2 : deg3);
    float* inv = gi == 0 ? inv1 : (gi == 1 ? inv2 : inv3);
    const int* prt = part + (gi == 0 ? 0 : (gi == 1 ? 256 : 288));
    int n = gi == 0 ? N0C : (gi == 1 ? N1C : N2C);
    int E = gi == 0 ? E1 : (gi == 1 ? E2 : E3);
    int i = lb * 256 + threadIdx.x;
    off[i] += prt[lb];
    inv[i] = 1.0f / fmaxf((float)deg[i], 1.0f);
    if (i == n - 1) off[n] = E;
}

__global__ __launch_bounds__(256)
void k_scatter3(const int* __restrict__ s1, const int* __restrict__ d1,
                const float* __restrict__ p1, const int* __restrict__ o1,
                int* __restrict__ c1, int* __restrict__ cs1, float2* __restrict__ cp1,
                const int* __restrict__ s2, const int* __restrict__ d2,
                const float* __restrict__ p2, const int* __restrict__ o2,
                int* __restrict__ c2, int* __restrict__ cs2, float2* __restrict__ cp2,
                const int* __restrict__ s3, const int* __restrict__ d3,
                const float* __restrict__ p3, const int* __restrict__ o3,
                int* __restrict__ c3, int* __restrict__ cs3, float2* __restrict__ cp3,
                int E1, int E2, int E3) {
    int i = blockIdx.x * 256 + threadIdx.x;
    const int* src; const int* dst; const float* pk; const int* off;
    int* cur; int* csrc; float2* cpk; int e;
    if (i < E1) { src = s1; dst = d1; pk = p1; off = o1; cur = c1; csrc = cs1; cpk = cp1; e = i; }
    else if (i < E1 + E2) { src = s2; dst = d2; pk = p2; off = o2; cur = c2; csrc = cs2; cpk = cp2; e = i - E1; }
    else if (i < E1 + E2 + E3) { src = s3; dst = d3; pk = p3; off = o3; cur = c3; csrc = cs3; cpk = cp3; e = i - E1 - E2; }
    else return;
    int d = dst[e];
    int p = off[d] + atomicAdd(&cur[d], 1);
    csrc[p] = src[e];
    cpk[p] = reinterpret_cast<const float2*>(pk)[e];
}

// ---------------- batched gw precompute (5 layer-graph pairs) --------------
// slot order: L1(E1) | L5(E1) | L2(E2) | L4(E2) | L3(E3); 12 floats/slot.
__global__ __launch_bounds__(256)
void k_gw(const float2* __restrict__ cp1, const float2* __restrict__ cp2,
          const float2* __restrict__ cp3,
          const float* __restrict__ mu1, const float* __restrict__ is1,
          const float* __restrict__ mu5, const float* __restrict__ is5,
          const float* __restrict__ mu2, const float* __restrict__ is2,
          const float* __restrict__ mu4, const float* __restrict__ is4,
          const float* __restrict__ mu3, const float* __restrict__ is3,
          float* __restrict__ g1, float* __restrict__ g5, float* __restrict__ g2,
          float* __restrict__ g4, float* __restrict__ g3,
          int E1, int E2, int E3) {
    int i = blockIdx.x * 256 + threadIdx.x;
    const float2* cp; const float* mu; const float* isg; float* g; int e;
    if (i < E1) { cp = cp1; mu = mu1; isg = is1; g = g1; e = i; }
    else if (i < 2 * E1) { cp = cp1; mu = mu5; isg = is5; g = g5; e = i - E1; }
    else if (i < 2 * E1 + E2) { cp = cp2; mu = mu2; isg = is2; g = g2; e = i - 2 * E1; }
    else if (i < 2 * E1 + 2 * E2) { cp = cp2; mu = mu4; isg = is4; g = g4; e = i - 2 * E1 - E2; }
    else if (i < 2 * E1 + 2 * E2 + E3) { cp = cp3; mu = mu3; isg = is3; g = g3; e = i - 2 * E1 - 2 * E2; }
    else return;
    float2 pk = cp[e];
    float o[KK];
#pragma unroll
    for (int k = 0; k < KK; ++k) {
        float dx = (pk.x - mu[2 * k]) * isg[2 * k];
        float dy = (pk.y - mu[2 * k + 1]) * isg[2 * k + 1];
        o[k] = __expf(-0.5f * (dx * dx + dy * dy));
    }
    float4* gp = reinterpret_cast<float4*>(g + (size_t)e * 12);
    gp[0] = make_float4(o[0], o[1], o[2], o[3]);
    gp[1] = make_float4(o[4], o[5], o[6], o[7]);
    gp[2] = make_float4(o[8], o[9], 0.f, 0.f);
}

#define LOAD_G(gw, j, G)                                                     \
    float G[KK];                                                             \
    {                                                                        \
        const float4* gp_ = reinterpret_cast<const float4*>((gw) + (size_t)(j) * 12); \
        float4 g0_ = gp_[0], g1_ = gp_[1]; float2 g2_ = *reinterpret_cast<const float2*>(gp_ + 2); \
        G[0] = g0_.x; G[1] = g0_.y; G[2] = g0_.z; G[3] = g0_.w;              \
        G[4] = g1_.x; G[5] = g1_.y; G[6] = g1_.z; G[7] = g1_.w;              \
        G[8] = g2_.x; G[9] = g2_.y;                                          \
    }

// ---------------- batched weight prep: Wt[f][k*Cin+c] = W[c][k*F+f] fp16 ----
__global__ __launch_bounds__(256)
void k_prep_wt(const float* __restrict__ W1, const float* __restrict__ W2,
               const float* __restrict__ W3, const float* __restrict__ W4,
               const float* __restrict__ W5,
               _Float16* __restrict__ T1, _Float16* __restrict__ T2,
               _Float16* __restrict__ T3, _Float16* __restrict__ T4,
               _Float16* __restrict__ T5) {
    int id = blockIdx.x * 256 + threadIdx.x;
    if (id < 1024) {                       // Wt1: F=32, KD=32 (Cin=2, pad 20->32)
        int f = id / 32, kc = id % 32;
        float v = (kc < 20) ? W1[(kc % 2) * 320 + (kc / 2) * 32 + f] : 0.0f;
        T1[id] = (_Float16)v;
        return;
    }
    id -= 1024;
    if (id < 20480) {                      // Wt2: F=64, KD=320 (Cin=32)
        int f = id / 320, kc = id % 320;
        T2[id] = (_Float16)W2[(kc % 32) * 640 + (kc / 32) * 64 + f];
        return;
    }
    id -= 20480;
    if (id < 81920) {                      // Wt3: F=128, KD=640 (Cin=64)
        int f = id / 640, kc = id % 640;
        T3[id] = (_Float16)W3[(kc % 64) * 1280 + (kc / 64) * 128 + f];
        return;
    }
    id -= 81920;
    if (id < 122880) {                     // Wt4: F=64, KD=1920 (Cin=192)
        int f = id / 1920, kc = id % 1920;
        T4[id] = (_Float16)W4[(kc % 192) * 640 + (kc / 192) * 64 + f];
        return;
    }
    id -= 122880;
    if (id < 46080) {                      // Wt5: F=48 (store 40), KD=960 (Cin=96)
        int f = id / 960, kc = id % 960;
        float v = (f < 40) ? W5[(kc % 96) * 400 + (kc / 96) * 40 + f] : 0.0f;
        T5[id] = (_Float16)v;
    }
}

// ---------------- L1 aggregate-X (Cin=2): 1 thread/node ----------
__global__ __launch_bounds__(256, 4)
void k_aggx1(const float* __restrict__ x, const int* __restrict__ off,
             const int* __restrict__ csrc, const float* __restrict__ gw,
             const float* __restrict__ inv, _Float16* __restrict__ agg) {
    int n = blockIdx.x * 256 + threadIdx.x;
    if (n >= N0C) return;
    float a0[KK], a1[KK];
#pragma unroll
    for (int k = 0; k < KK; ++k) { a0[k] = 0.f; a1[k] = 0.f; }
    int j0 = off[n], j1 = off[n + 1];
    for (int j = j0; j < j1; ++j) {
        int s = csrc[j];
        LOAD_G(gw, j, G)
        float2 xv = reinterpret_cast<const float2*>(x)[s];
#pragma unroll
        for (int k = 0; k < KK; ++k) {
            a0[k] = fmaf(G[k], xv.x, a0[k]);
            a1[k] = fmaf(G[k], xv.y, a1[k]);
        }
    }
    float iv = inv[n];
    f16x8 v[4];
#pragma unroll
    for (int u = 0; u < 4; ++u)
#pragma unroll
        for (int e = 0; e < 8; ++e) {
            int kc = u * 8 + e;
            float val = (kc < 20) ? ((kc & 1) ? a1[kc >> 1] : a0[kc >> 1]) * iv : 0.f;
            v[u][e] = (_Float16)val;
        }
    f16x8* out = reinterpret_cast<f16x8*>(agg + (size_t)n * 32);
#pragma unroll
    for (int u = 0; u < 4; ++u) out[u] = v[u];
}

// ---------------- split aggregate-X (fp16 src) for L2/L3 ----------
template <int TPN>
__global__ __launch_bounds__(256, 4)
void k_aggx(const _Float16* __restrict__ xp, const int* __restrict__ off,
            const int* __restrict__ csrc, const float* __restrict__ gw,
            const float* __restrict__ inv, _Float16* __restrict__ agg, int N) {
    constexpr int CIN = TPN * 4;
    constexpr int KD = KK * CIN;
    int tid = threadIdx.x;
    int nl = tid / TPN, tt = tid - nl * TPN;
    int node = blockIdx.x * (256 / TPN) + nl;
    if (node >= N) return;
    float a[KK][4];
#pragma unroll
    for (int k = 0; k < KK; ++k)
#pragma unroll
        for (int e = 0; e < 4; ++e) a[k][e] = 0.f;
    int j0 = off[node], j1 = off[node + 1];
    for (int j = j0; j < j1; ++j) {
        int s = csrc[j];
        LOAD_G(gw, j, G)
        half4 hv = *reinterpret_cast<const half4*>(xp + (size_t)s * CIN + 4 * tt);
        float x0 = hv[0], x1 = hv[1], x2 = hv[2], x3 = hv[3];
#pragma unroll
        for (int k = 0; k < KK; ++k) {
            a[k][0] = fmaf(G[k], x0, a[k][0]);
            a[k][1] = fmaf(G[k], x1, a[k][1]);
            a[k][2] = fmaf(G[k], x2, a[k][2]);
            a[k][3] = fmaf(G[k], x3, a[k][3]);
        }
    }
    float iv = inv[node];
#pragma unroll
    for (int k = 0; k < KK; ++k) {
        half4 o;
        o[0] = (_Float16)(a[k][0] * iv); o[1] = (_Float16)(a[k][1] * iv);
        o[2] = (_Float16)(a[k][2] * iv); o[3] = (_Float16)(a[k][3] * iv);
        *reinterpret_cast<half4*>(agg + (size_t)node * KD + k * CIN + 4 * tt) = o;
    }
}

// ---------------- L4/L5 aggregate (fp32 concat src, upsample fused) --------
template <int CA, int CB, int TPN, int NPB>
__global__ __launch_bounds__(TPN * NPB, 3)
void k_aggf(const float* __restrict__ xA, const float* __restrict__ xB,
            const int* __restrict__ off, const int* __restrict__ csrc,
            const float* __restrict__ gw, const float* __restrict__ inv,
            _Float16* __restrict__ agg, int nodeBase) {
    constexpr int CIN = CA + CB;
    constexpr int KD = KK * CIN;
    const int tid = threadIdx.x;
    int nl = tid / TPN, tt = tid - nl * TPN;
    int lnode = blockIdx.x * NPB + nl;
    int node = nodeBase + lnode;
    int c0 = 8 * tt;
    float a[KK][8];
#pragma unroll
    for (int k = 0; k < KK; ++k)
#pragma unroll
        for (int e = 0; e < 8; ++e) a[k][e] = 0.f;
    int j0 = off[node], j1 = off[node + 1];
    for (int j = j0; j < j1; ++j) {
        int s = csrc[j];
        LOAD_G(gw, j, G)
        const float* bsrc = (c0 < CA) ? (xA + (size_t)(s >> 3) * CA + c0)
                                      : (xB + (size_t)s * CB + (c0 - CA));
        float4 xa = reinterpret_cast<const float4*>(bsrc)[0];
        float4 xb = reinterpret_cast<const float4*>(bsrc)[1];
#pragma unroll
        for (int k = 0; k < KK; ++k) {
            a[k][0] = fmaf(G[k], xa.x, a[k][0]);
            a[k][1] = fmaf(G[k], xa.y, a[k][1]);
            a[k][2] = fmaf(G[k], xa.z, a[k][2]);
            a[k][3] = fmaf(G[k], xa.w, a[k][3]);
            a[k][4] = fmaf(G[k], xb.x, a[k][4]);
            a[k][5] = fmaf(G[k], xb.y, a[k][5]);
            a[k][6] = fmaf(G[k], xb.z, a[k][6]);
            a[k][7] = fmaf(G[k], xb.w, a[k][7]);
        }
    }
    float iv = inv[node];
#pragma unroll
    for (int k = 0; k < KK; ++k) {
        f16x8 v;
#pragma unroll
        for (int e = 0; e < 8; ++e) v[e] = (_Float16)(a[k][e] * iv);
        *reinterpret_cast<f16x8*>(agg + (size_t)lnode * KD + k * CIN + c0) = v;
    }
}

// ---------------- MFMA GEMM + epilogue ----------------
template <int WB, int NT, int ACT, int FST>
__global__ __launch_bounds__(WB * 64)
void k_gemm_epi(const _Float16* __restrict__ A, const _Float16* __restrict__ Wt,
                const float* __restrict__ bias, float* __restrict__ out, int KD) {
    const int lane = threadIdx.x & 63;
    const int wv = threadIdx.x >> 6;
    const int lm = lane & 15;
    const int q = lane >> 4;
    const size_t m0 = (size_t)blockIdx.y * (WB * 16) + wv * 16;
    f32x4 acc[NT];
#pragma unroll
    for (int t = 0; t < NT; ++t) acc[t] = (f32x4){0.f, 0.f, 0.f, 0.f};
    const _Float16* ap = A + (m0 + lm) * (size_t)KD + q * 8;
    const _Float16* bp = Wt + (size_t)lm * KD + q * 8;
    for (int kt = 0; kt < KD; kt += 32) {
        f16x8 af = *(const f16x8*)(ap + kt);
#pragma unroll
        for (int t = 0; t < NT; ++t) {
            f16x8 bf = *(const f16x8*)(bp + (size_t)t * 16 * KD + kt);
            acc[t] = __builtin_amdgcn_mfma_f32_16x16x32_f16(af, bf, acc[t], 0, 0, 0);
        }
    }
#pragma unroll
    for (int t = 0; t < NT; ++t) {
        int f = t * 16 + lm;
        if (f < FST) {
            float b = bias ? bias[f] : 0.0f;
#pragma unroll
            for (int r = 0; r < 4; ++r) {
                float v = acc[t][r] + b;
                v = (ACT == 1) ? tanhf(v) : fmaxf(v, 0.0f);
                out[(m0 + q * 4 + r) * (size_t)FST + f] = v;
            }
        }
    }
}

// out[j,f] = max over the 8 fine nodes of group j — emits fp16.
__global__ __launch_bounds__(256)
void k_pool8h(const float* __restrict__ in, _Float16* __restrict__ out, int total, int F) {
    int i = blockIdx.x * 256 + threadIdx.x;
    if (i >= total) return;
    int j = i / F;
    int f = i - j * F;
    const float* p = in + (size_t)(j << 3) * F + f;
    float m = p[0];
#pragma unroll
    for (int r = 1; r < 8; ++r) m = fmaxf(m, p[(size_t)r * F]);
    out[i] = (_Float16)m;
}

extern "C" void kernel_launch(void* const* d_in, const int* in_sizes, int n_in,
                              void* d_out, int out_size, void* d_ws, size_t ws_size,
                              hipStream_t stream) {
    const float* n_feat = (const float*)d_in[0];
    const int* src1 = (const int*)d_in[1];
    const int* dst1 = (const int*)d_in[2];
    const float* pkor1 = (const float*)d_in[3];
    const int* src2 = (const int*)d_in[4];
    const int* dst2 = (const int*)d_in[5];
    const float* pkor2 = (const float*)d_in[6];
    const int* src3 = (const int*)d_in[7];
    const int* dst3 = (const int*)d_in[8];
    const float* pkor3 = (const float*)d_in[9];
    const float* W1 = (const float*)d_in[16];
    const float* mu1 = (const float*)d_in[17];
    const float* is1 = (const float*)d_in[18];
    const float* b1 = (const float*)d_in[19];
    const float* W2 = (const float*)d_in[20];
    const float* mu2 = (const float*)d_in[21];
    const float* is2 = (const float*)d_in[22];
    const float* W3 = (const float*)d_in[23];
    const float* mu3 = (const float*)d_in[24];
    const float* is3 = (const float*)d_in[25];
    const float* W4 = (const float*)d_in[26];
    const float* mu4 = (const float*)d_in[27];
    const float* is4 = (const float*)d_in[28];
    const float* W5 = (const float*)d_in[29];
    const float* mu5 = (const float*)d_in[30];
    const float* is5 = (const float*)d_in[31];
    const float* b5 = (const float*)d_in[32];

    const int E1 = in_sizes[1], E2 = in_sizes[4], E3 = in_sizes[7];
    const int NT_ = N0C + N1C + N2C;

    char* w = (char*)d_ws;
    auto alloc = [&](size_t bytes) {
        void* p = (void*)w;
        w += (bytes + 255) & ~(size_t)255;
        return p;
    };
    int* degs = (int*)alloc((size_t)NT_ * 2 * 4);
    int* deg1 = degs, *deg2 = degs + N0C, *deg3 = degs + N0C + N1C;
    int* cur1 = degs + NT_, *cur2 = cur1 + N0C, *cur3 = cur2 + N1C;
    int* off1 = (int*)alloc(((size_t)N0C + 1) * 4);
    int* off2 = (int*)alloc(((size_t)N1C + 1) * 4);
    int* off3 = (int*)alloc(((size_t)N2C + 1) * 4);
    int* part = (int*)alloc(292 * 4);
    int* csrc1 = (int*)alloc((size_t)E1 * 4);
    float2* cpk1 = (float2*)alloc((size_t)E1 * 8);
    int* csrc2 = (int*)alloc((size_t)E2 * 4);
    float2* cpk2 = (float2*)alloc((size_t)E2 * 8);
    int* csrc3 = (int*)alloc((size_t)E3 * 4);
    float2* cpk3 = (float2*)alloc((size_t)E3 * 8);
    float* inv1 = (float*)alloc((size_t)N0C * 4);
    float* inv2 = (float*)alloc((size_t)N1C * 4);
    float* inv3 = (float*)alloc((size_t)N2C * 4);
    // gw buffers (12 floats per CSR slot): L1|L5|L2|L4|L3
    float* g1 = (float*)alloc(((size_t)2 * E1 + 2 * E2 + E3) * 12 * 4);
    float* g5 = g1 + (size_t)E1 * 12;
    float* g2 = g5 + (size_t)E1 * 12;
    float* g4 = g2 + (size_t)E2 * 12;
    float* g3 = g4 + (size_t)E2 * 12;
    float* out0 = (float*)alloc((size_t)N0C * 32 * 4);
    float* out1 = (float*)alloc((size_t)N1C * 64 * 4);
    float* out2 = (float*)alloc((size_t)N2C * 128 * 4);
    float* out3 = (float*)alloc((size_t)N1C * 64 * 4);
    _Float16* hp1 = (_Float16*)alloc((size_t)N1C * 32 * 2);
    _Float16* hp2 = (_Float16*)alloc((size_t)N2C * 64 * 2);
    _Float16* agg1 = (_Float16*)alloc((size_t)N0C * 32 * 2);
    _Float16* agg2 = (_Float16*)alloc((size_t)N1C * 320 * 2);
    _Float16* agg3 = (_Float16*)alloc((size_t)N2C * 640 * 2);
    _Float16* Wt1 = (_Float16*)alloc((size_t)32 * 32 * 2);
    _Float16* Wt2 = (_Float16*)alloc((size_t)64 * 320 * 2);
    _Float16* Wt3 = (_Float16*)alloc((size_t)128 * 640 * 2);
    _Float16* Wt4 = (_Float16*)alloc((size_t)64 * 1920 * 2);
    _Float16* Wt5 = (_Float16*)alloc((size_t)48 * 960 * 2);
    size_t used = (size_t)(w - (char*)d_ws);
    size_t rem = (ws_size > used) ? (ws_size - used) : 0;
    _Float16* agg4 = (_Float16*)w;
    _Float16* agg5 = (_Float16*)w;
    int npass = 1;
    while ((size_t)(N0C / npass) * 960 * 2 > rem && npass < 16) npass <<= 1;
    const int chunk = N0C / npass;

    const int ET = E1 + E2 + E3;
    const int GT = 2 * E1 + 2 * E2 + E3;

    // ---- CSR build (batched) + weight prep + gw precompute
    hipMemsetAsync(degs, 0, (size_t)NT_ * 2 * 4, stream);
    k_prep_wt<<<cdiv(272384, 256), 256, 0, stream>>>(W1, W2, W3, W4, W5,
                                                     Wt1, Wt2, Wt3, Wt4, Wt5);
    k_hist3<<<cdiv(ET, 256), 256, 0, stream>>>(dst1, dst2, dst3, deg1, deg2, deg3, E1, E2, E3);
    k_scan1_3<<<292, 256, 0, stream>>>(deg1, off1, deg2, off2, deg3, off3, part);
    k_scan2_3<<<3, 256, 0, stream>>>(part);
    k_scan3_3<<<292, 256, 0, stream>>>(off1, off2, off3, part, deg1, deg2, deg3,
                                       inv1, inv2, inv3, E1, E2, E3);
    k_scatter3<<<cdiv(ET, 256), 256, 0, stream>>>(
        src1, dst1, pkor1, off1, cur1, csrc1, cpk1,
        src2, dst2, pkor2, off2, cur2, csrc2, cpk2,
        src3, dst3, pkor3, off3, cur3, csrc3, cpk3, E1, E2, E3);
    k_gw<<<cdiv(GT, 256), 256, 0, stream>>>(
        cpk1, cpk2, cpk3, mu1, is1, mu5, is5, mu2, is2, mu4, is4, mu3, is3,
        g1, g5, g2, g4, g3, E1, E2, E3);

    // ---- L1: aggX (Cin=2) -> agg1; GEMM+b1+relu -> out0 (N0,32)
    k_aggx1<<<N0C / 256, 256, 0, stream>>>(n_feat, off1, csrc1, g1, inv1, agg1);
    k_gemm_epi<4, 2, 0, 32><<<dim3(1, N0C / 64), 256, 0, stream>>>(agg1, Wt1, b1, out0, 32);

    // ---- L2: pool -> aggX (Cin=32) -> agg2; GEMM+relu -> out1 (N1,64)
    k_pool8h<<<cdiv(N1C * 32, 256), 256, 0, stream>>>(out0, hp1, N1C * 32, 32);
    k_aggx<8><<<cdiv(N1C, 32), 256, 0, stream>>>(hp1, off2, csrc2, g2, inv2, agg2, N1C);
    k_gemm_epi<2, 4, 0, 64><<<dim3(1, N1C / 32), 128, 0, stream>>>(agg2, Wt2, nullptr, out1, 320);

    // ---- L3: pool -> aggX (Cin=64) -> agg3; GEMM+relu -> out2 (N2,128)
    k_pool8h<<<cdiv(N2C * 64, 256), 256, 0, stream>>>(out1, hp2, N2C * 64, 64);
    k_aggx<16><<<cdiv(N2C, 16), 256, 0, stream>>>(hp2, off3, csrc3, g3, inv3, agg3, N2C);
    k_gemm_epi<1, 8, 0, 128><<<dim3(1, N2C / 16), 64, 0, stream>>>(agg3, Wt3, nullptr, out2, 640);

    // ---- L4: aggF (X=[up(out2)|out1], Cin=192) -> agg4; GEMM+relu -> out3
    k_aggf<128, 64, 24, 16><<<N1C / 16, 384, 0, stream>>>(
        out2, out1, off2, csrc2, g4, inv2, agg4, 0);
    k_gemm_epi<2, 4, 0, 64><<<dim3(1, N1C / 32), 128, 0, stream>>>(agg4, Wt4, nullptr, out3, 1920);

    // ---- L5: aggF (X=[up(out3)|out0], Cin=96) -> agg5 (chunked); GEMM+b5+tanh
    for (int p = 0; p < npass; ++p) {
        int base = p * chunk;
        k_aggf<64, 32, 12, 32><<<chunk / 32, 384, 0, stream>>>(
            out3, out0, off1, csrc1, g5, inv1, agg5, base);
        k_gemm_epi<4, 3, 1, 40><<<dim3(1, chunk / 64), 256, 0, stream>>>(
            agg5, Wt5, b5, ((float*)d_out) + (size_t)base * 40, 960);
    }
}

// Round 9
// 412.822 us; speedup vs baseline: 1.1222x; 1.1222x over previous
//
#include <hip/hip_runtime.h>

// ---------------------------------------------------------------------------
// UNet_old (graph U-Net, GMMConv K=10) on MI355X. fp32 in / fp32 out.
// R9: latency-bound GEMM fix (R8: L5 GEMM 59.8us @ MfmaUtil 3.5%, occ 36%,
// 1 TB/s effective — too few waves + serial K-loop).
//  - k_gemm2: compile-time KD, fully unrolled K-loop with 1-deep register
//    prefetch (load i+1 fragments before MFMAs of i).
//  - split-K for deep-K GEMMs: L5 KS=3, L4 KS=4 -> 3-4x wave count; fp32
//    partials + k_redact (sum + bias + act). L1/L2/L3: KS=1, fused epilogue.
// Aggregation kernels unchanged from R8 (gw precomputed per CSR slot).
// ---------------------------------------------------------------------------

#define N0C 65536
#define N1C 8192
#define N2C 1024
#define KK 10

typedef _Float16 half4 __attribute__((ext_vector_type(4)));
typedef _Float16 f16x8 __attribute__((ext_vector_type(8)));
typedef float f32x4 __attribute__((ext_vector_type(4)));

static inline int cdiv(long long a, long long b) { return (int)((a + b - 1) / b); }

// ---------------- batched CSR build (3 graphs) ----------------

__global__ __launch_bounds__(256)
void k_hist3(const int* __restrict__ d1, const int* __restrict__ d2,
             const int* __restrict__ d3, int* __restrict__ g1,
             int* __restrict__ g2, int* __restrict__ g3,
             int E1, int E2, int E3) {
    int i = blockIdx.x * 256 + threadIdx.x;
    if (i < E1) atomicAdd(&g1[d1[i]], 1);
    else if (i < E1 + E2) atomicAdd(&g2[d2[i - E1]], 1);
    else if (i < E1 + E2 + E3) atomicAdd(&g3[d3[i - E1 - E2]], 1);
}

__device__ __forceinline__ void map_graph(int b, int& lb, int& gi) {
    if (b < 256) { gi = 0; lb = b; }
    else if (b < 288) { gi = 1; lb = b - 256; }
    else { gi = 2; lb = b - 288; }
}

__global__ __launch_bounds__(256)
void k_scan1_3(const int* __restrict__ deg1, int* __restrict__ off1,
               const int* __restrict__ deg2, int* __restrict__ off2,
               const int* __restrict__ deg3, int* __restrict__ off3,
               int* __restrict__ part) {
    __shared__ int s[256];
    int lb, gi; map_graph(blockIdx.x, lb, gi);
    const int* deg = gi == 0 ? deg1 : (gi == 1 ? deg2 : deg3);
    int* off = gi == 0 ? off1 : (gi == 1 ? off2 : off3);
    int* prt = part + (gi == 0 ? 0 : (gi == 1 ? 256 : 288));
    int i = lb * 256 + threadIdx.x;
    int v = deg[i];
    s[threadIdx.x] = v;
    __syncthreads();
#pragma unroll
    for (int d = 1; d < 256; d <<= 1) {
        int t = (threadIdx.x >= d) ? s[threadIdx.x - d] : 0;
        __syncthreads();
        s[threadIdx.x] += t;
        __syncthreads();
    }
    off[i] = s[threadIdx.x] - v;
    if (threadIdx.x == 255) prt[lb] = s[255];
}

__global__ __launch_bounds__(256)
void k_scan2_3(int* __restrict__ part) {
    __shared__ int s[256];
    int nb = blockIdx.x == 0 ? 256 : (blockIdx.x == 1 ? 32 : 4);
    int* p = part + (blockIdx.x == 0 ? 0 : (blockIdx.x == 1 ? 256 : 288));
    int v = (threadIdx.x < nb) ? p[threadIdx.x] : 0;
    s[threadIdx.x] = v;
    __syncthreads();
#pragma unroll
    for (int d = 1; d < 256; d <<= 1) {
        int t = (threadIdx.x >= d) ? s[threadIdx.x - d] : 0;
        __syncthreads();
        s[threadIdx.x] += t;
        __syncthreads();
    }
    if (threadIdx.x < nb) p[threadIdx.x] = s[threadIdx.x] - v;
}

__global__ __launch_bounds__(256)
void k_scan3_3(int* __restrict__ off1, int* __restrict__ off2, int* __restrict__ off3,
               const int* __restrict__ part,
               const int* __restrict__ deg1, const int* __restrict__ deg2,
               const int* __restrict__ deg3,
               float* __restrict__ inv1, float* __restrict__ inv2,
               float* __restrict__ inv3, int E1, int E2, int E3) {
    int lb, gi; map_graph(blockIdx.x, lb, gi);
    int* off = gi == 0 ? off1 : (gi == 1 ? off2 : off3);
    const int* deg = gi == 0 ? deg1 : (gi == 1 ? deg2 : deg3);
    float* inv = gi == 0 ? inv1 : (gi == 1 ? inv2 : inv3);
    const int* prt = part + (gi == 0 ? 0 : (gi == 1 ? 256 : 288));
    int n = gi == 0 ? N0C : (gi == 1 ? N1C : N2C);
    int E = gi == 0 ? E1 : (gi == 1 ? E2 : E3);
    int i = lb * 256 + threadIdx.x;
    off[i] += prt[lb];
    inv[i] = 1.0f / fmaxf((float)deg[i], 1.0f);
    if (i == n - 1) off[n] = E;
}

__global__ __launch_bounds__(256)
void k_scatter3(const int* __restrict__ s1, const int* __restrict__ d1,
                const float* __restrict__ p1, const int* __restrict__ o1,
                int* __restrict__ c1, int* __restrict__ cs1, float2* __restrict__ cp1,
                const int* __restrict__ s2, const int* __restrict__ d2,
                const float* __restrict__ p2, const int* __restrict__ o2,
                int* __restrict__ c2, int* __restrict__ cs2, float2* __restrict__ cp2,
                const int* __restrict__ s3, const int* __restrict__ d3,
                const float* __restrict__ p3, const int* __restrict__ o3,
                int* __restrict__ c3, int* __restrict__ cs3, float2* __restrict__ cp3,
                int E1, int E2, int E3) {
    int i = blockIdx.x * 256 + threadIdx.x;
    const int* src; const int* dst; const float* pk; const int* off;
    int* cur; int* csrc; float2* cpk; int e;
    if (i < E1) { src = s1; dst = d1; pk = p1; off = o1; cur = c1; csrc = cs1; cpk = cp1; e = i; }
    else if (i < E1 + E2) { src = s2; dst = d2; pk = p2; off = o2; cur = c2; csrc = cs2; cpk = cp2; e = i - E1; }
    else if (i < E1 + E2 + E3) { src = s3; dst = d3; pk = p3; off = o3; cur = c3; csrc = cs3; cpk = cp3; e = i - E1 - E2; }
    else return;
    int d = dst[e];
    int p = off[d] + atomicAdd(&cur[d], 1);
    csrc[p] = src[e];
    cpk[p] = reinterpret_cast<const float2*>(pk)[e];
}

// ---------------- batched gw precompute (5 layer-graph pairs) --------------
// slot order: L1(E1) | L5(E1) | L2(E2) | L4(E2) | L3(E3); 12 floats/slot.
__global__ __launch_bounds__(256)
void k_gw(const float2* __restrict__ cp1, const float2* __restrict__ cp2,
          const float2* __restrict__ cp3,
          const float* __restrict__ mu1, const float* __restrict__ is1,
          const float* __restrict__ mu5, const float* __restrict__ is5,
          const float* __restrict__ mu2, const float* __restrict__ is2,
          const float* __restrict__ mu4, const float* __restrict__ is4,
          const float* __restrict__ mu3, const float* __restrict__ is3,
          float* __restrict__ g1, float* __restrict__ g5, float* __restrict__ g2,
          float* __restrict__ g4, float* __restrict__ g3,
          int E1, int E2, int E3) {
    int i = blockIdx.x * 256 + threadIdx.x;
    const float2* cp; const float* mu; const float* isg; float* g; int e;
    if (i < E1) { cp = cp1; mu = mu1; isg = is1; g = g1; e = i; }
    else if (i < 2 * E1) { cp = cp1; mu = mu5; isg = is5; g = g5; e = i - E1; }
    else if (i < 2 * E1 + E2) { cp = cp2; mu = mu2; isg = is2; g = g2; e = i - 2 * E1; }
    else if (i < 2 * E1 + 2 * E2) { cp = cp2; mu = mu4; isg = is4; g = g4; e = i - 2 * E1 - E2; }
    else if (i < 2 * E1 + 2 * E2 + E3) { cp = cp3; mu = mu3; isg = is3; g = g3; e = i - 2 * E1 - 2 * E2; }
    else return;
    float2 pk = cp[e];
    float o[KK];
#pragma unroll
    for (int k = 0; k < KK; ++k) {
        float dx = (pk.x - mu[2 * k]) * isg[2 * k];
        float dy = (pk.y - mu[2 * k + 1]) * isg[2 * k + 1];
        o[k] = __expf(-0.5f * (dx * dx + dy * dy));
    }
    float4* gp = reinterpret_cast<float4*>(g + (size_t)e * 12);
    gp[0] = make_float4(o[0], o[1], o[2], o[3]);
    gp[1] = make_float4(o[4], o[5], o[6], o[7]);
    gp[2] = make_float4(o[8], o[9], 0.f, 0.f);
}

#define LOAD_G(gw, j, G)                                                     \
    float G[KK];                                                             \
    {                                                                        \
        const float4* gp_ = reinterpret_cast<const float4*>((gw) + (size_t)(j) * 12); \
        float4 g0_ = gp_[0], g1_ = gp_[1]; float2 g2_ = *reinterpret_cast<const float2*>(gp_ + 2); \
        G[0] = g0_.x; G[1] = g0_.y; G[2] = g0_.z; G[3] = g0_.w;              \
        G[4] = g1_.x; G[5] = g1_.y; G[6] = g1_.z; G[7] = g1_.w;              \
        G[8] = g2_.x; G[9] = g2_.y;                                          \
    }

// ---------------- batched weight prep: Wt[f][k*Cin+c] = W[c][k*F+f] fp16 ----
__global__ __launch_bounds__(256)
void k_prep_wt(const float* __restrict__ W1, const float* __restrict__ W2,
               const float* __restrict__ W3, const float* __restrict__ W4,
               const float* __restrict__ W5,
               _Float16* __restrict__ T1, _Float16* __restrict__ T2,
               _Float16* __restrict__ T3, _Float16* __restrict__ T4,
               _Float16* __restrict__ T5) {
    int id = blockIdx.x * 256 + threadIdx.x;
    if (id < 1024) {                       // Wt1: F=32, KD=32 (Cin=2, pad 20->32)
        int f = id / 32, kc = id % 32;
        float v = (kc < 20) ? W1[(kc % 2) * 320 + (kc / 2) * 32 + f] : 0.0f;
        T1[id] = (_Float16)v;
        return;
    }
    id -= 1024;
    if (id < 20480) {                      // Wt2: F=64, KD=320 (Cin=32)
        int f = id / 320, kc = id % 320;
        T2[id] = (_Float16)W2[(kc % 32) * 640 + (kc / 32) * 64 + f];
        return;
    }
    id -= 20480;
    if (id < 81920) {                      // Wt3: F=128, KD=640 (Cin=64)
        int f = id / 640, kc = id % 640;
        T3[id] = (_Float16)W3[(kc % 64) * 1280 + (kc / 64) * 128 + f];
        return;
    }
    id -= 81920;
    if (id < 122880) {                     // Wt4: F=64, KD=1920 (Cin=192)
        int f = id / 1920, kc = id % 1920;
        T4[id] = (_Float16)W4[(kc % 192) * 640 + (kc / 192) * 64 + f];
        return;
    }
    id -= 122880;
    if (id < 46080) {                      // Wt5: F=48 (store 40), KD=960 (Cin=96)
        int f = id / 960, kc = id % 960;
        float v = (f < 40) ? W5[(kc % 96) * 400 + (kc / 96) * 40 + f] : 0.0f;
        T5[id] = (_Float16)v;
    }
}

// ---------------- L1 aggregate-X (Cin=2): 1 thread/node ----------
__global__ __launch_bounds__(256, 4)
void k_aggx1(const float* __restrict__ x, const int* __restrict__ off,
             const int* __restrict__ csrc, const float* __restrict__ gw,
             const float* __restrict__ inv, _Float16* __restrict__ agg) {
    int n = blockIdx.x * 256 + threadIdx.x;
    if (n >= N0C) return;
    float a0[KK], a1[KK];
#pragma unroll
    for (int k = 0; k < KK; ++k) { a0[k] = 0.f; a1[k] = 0.f; }
    int j0 = off[n], j1 = off[n + 1];
    for (int j = j0; j < j1; ++j) {
        int s = csrc[j];
        LOAD_G(gw, j, G)
        float2 xv = reinterpret_cast<const float2*>(x)[s];
#pragma unroll
        for (int k = 0; k < KK; ++k) {
            a0[k] = fmaf(G[k], xv.x, a0[k]);
            a1[k] = fmaf(G[k], xv.y, a1[k]);
        }
    }
    float iv = inv[n];
    f16x8 v[4];
#pragma unroll
    for (int u = 0; u < 4; ++u)
#pragma unroll
        for (int e = 0; e < 8; ++e) {
            int kc = u * 8 + e;
            float val = (kc < 20) ? ((kc & 1) ? a1[kc >> 1] : a0[kc >> 1]) * iv : 0.f;
            v[u][e] = (_Float16)val;
        }
    f16x8* out = reinterpret_cast<f16x8*>(agg + (size_t)n * 32);
#pragma unroll
    for (int u = 0; u < 4; ++u) out[u] = v[u];
}

// ---------------- split aggregate-X (fp16 src) for L2/L3 ----------
template <int TPN>
__global__ __launch_bounds__(256, 4)
void k_aggx(const _Float16* __restrict__ xp, const int* __restrict__ off,
            const int* __restrict__ csrc, const float* __restrict__ gw,
            const float* __restrict__ inv, _Float16* __restrict__ agg, int N) {
    constexpr int CIN = TPN * 4;
    constexpr int KD = KK * CIN;
    int tid = threadIdx.x;
    int nl = tid / TPN, tt = tid - nl * TPN;
    int node = blockIdx.x * (256 / TPN) + nl;
    if (node >= N) return;
    float a[KK][4];
#pragma unroll
    for (int k = 0; k < KK; ++k)
#pragma unroll
        for (int e = 0; e < 4; ++e) a[k][e] = 0.f;
    int j0 = off[node], j1 = off[node + 1];
    for (int j = j0; j < j1; ++j) {
        int s = csrc[j];
        LOAD_G(gw, j, G)
        half4 hv = *reinterpret_cast<const half4*>(xp + (size_t)s * CIN + 4 * tt);
        float x0 = hv[0], x1 = hv[1], x2 = hv[2], x3 = hv[3];
#pragma unroll
        for (int k = 0; k < KK; ++k) {
            a[k][0] = fmaf(G[k], x0, a[k][0]);
            a[k][1] = fmaf(G[k], x1, a[k][1]);
            a[k][2] = fmaf(G[k], x2, a[k][2]);
            a[k][3] = fmaf(G[k], x3, a[k][3]);
        }
    }
    float iv = inv[node];
#pragma unroll
    for (int k = 0; k < KK; ++k) {
        half4 o;
        o[0] = (_Float16)(a[k][0] * iv); o[1] = (_Float16)(a[k][1] * iv);
        o[2] = (_Float16)(a[k][2] * iv); o[3] = (_Float16)(a[k][3] * iv);
        *reinterpret_cast<half4*>(agg + (size_t)node * KD + k * CIN + 4 * tt) = o;
    }
}

// ---------------- L4/L5 aggregate (fp32 concat src, upsample fused) --------
template <int CA, int CB, int TPN, int NPB>
__global__ __launch_bounds__(TPN * NPB, 3)
void k_aggf(const float* __restrict__ xA, const float* __restrict__ xB,
            const int* __restrict__ off, const int* __restrict__ csrc,
            const float* __restrict__ gw, const float* __restrict__ inv,
            _Float16* __restrict__ agg, int nodeBase) {
    constexpr int CIN = CA + CB;
    constexpr int KD = KK * CIN;
    const int tid = threadIdx.x;
    int nl = tid / TPN, tt = tid - nl * TPN;
    int lnode = blockIdx.x * NPB + nl;
    int node = nodeBase + lnode;
    int c0 = 8 * tt;
    float a[KK][8];
#pragma unroll
    for (int k = 0; k < KK; ++k)
#pragma unroll
        for (int e = 0; e < 8; ++e) a[k][e] = 0.f;
    int j0 = off[node], j1 = off[node + 1];
    for (int j = j0; j < j1; ++j) {
        int s = csrc[j];
        LOAD_G(gw, j, G)
        const float* bsrc = (c0 < CA) ? (xA + (size_t)(s >> 3) * CA + c0)
                                      : (xB + (size_t)s * CB + (c0 - CA));
        float4 xa = reinterpret_cast<const float4*>(bsrc)[0];
        float4 xb = reinterpret_cast<const float4*>(bsrc)[1];
#pragma unroll
        for (int k = 0; k < KK; ++k) {
            a[k][0] = fmaf(G[k], xa.x, a[k][0]);
            a[k][1] = fmaf(G[k], xa.y, a[k][1]);
            a[k][2] = fmaf(G[k], xa.z, a[k][2]);
            a[k][3] = fmaf(G[k], xa.w, a[k][3]);
            a[k][4] = fmaf(G[k], xb.x, a[k][4]);
            a[k][5] = fmaf(G[k], xb.y, a[k][5]);
            a[k][6] = fmaf(G[k], xb.z, a[k][6]);
            a[k][7] = fmaf(G[k], xb.w, a[k][7]);
        }
    }
    float iv = inv[node];
#pragma unroll
    for (int k = 0; k < KK; ++k) {
        f16x8 v;
#pragma unroll
        for (int e = 0; e < 8; ++e) v[e] = (_Float16)(a[k][e] * iv);
        *reinterpret_cast<f16x8*>(agg + (size_t)lnode * KD + k * CIN + c0) = v;
    }
}

// ---------------- pipelined split-K MFMA GEMM ----------------
// KD = KS*ITERS*32 (compile-time). KS==1: out = act(A@Wt^T + bias) (fp32,
// FST cols). KS>1: out = fp32 partials [ks][M][F], reduced by k_redact.
template <int WB, int NT, int ITERS, int KS, int ACT, int FST>
__global__ __launch_bounds__(WB * 64)
void k_gemm2(const _Float16* __restrict__ A, const _Float16* __restrict__ Wt,
             const float* __restrict__ bias, float* __restrict__ out, int M) {
    constexpr int KD = KS * ITERS * 32;
    constexpr int F = NT * 16;
    const int lane = threadIdx.x & 63;
    const int wv = threadIdx.x >> 6;
    const int lm = lane & 15;
    const int q = lane >> 4;
    const int ks = blockIdx.x;
    const int k0 = ks * ITERS * 32;
    const size_t m0 = (size_t)blockIdx.y * (WB * 16) + wv * 16;
    f32x4 acc[NT];
#pragma unroll
    for (int t = 0; t < NT; ++t) acc[t] = (f32x4){0.f, 0.f, 0.f, 0.f};
    const _Float16* ap = A + (m0 + lm) * (size_t)KD + q * 8 + k0;
    const _Float16* bp = Wt + (size_t)lm * KD + q * 8 + k0;
    f16x8 af = *(const f16x8*)ap;
    f16x8 bf[NT];
#pragma unroll
    for (int t = 0; t < NT; ++t) bf[t] = *(const f16x8*)(bp + (size_t)t * 16 * KD);
#pragma unroll
    for (int i = 0; i < ITERS; ++i) {
        f16x8 afn; f16x8 bfn[NT];
        if (i + 1 < ITERS) {
            afn = *(const f16x8*)(ap + 32 * (i + 1));
#pragma unroll
            for (int t = 0; t < NT; ++t)
                bfn[t] = *(const f16x8*)(bp + (size_t)t * 16 * KD + 32 * (i + 1));
        }
#pragma unroll
        for (int t = 0; t < NT; ++t)
            acc[t] = __builtin_amdgcn_mfma_f32_16x16x32_f16(af, bf[t], acc[t], 0, 0, 0);
        af = afn;
#pragma unroll
        for (int t = 0; t < NT; ++t) bf[t] = bfn[t];
    }
    if (KS == 1) {
#pragma unroll
        for (int t = 0; t < NT; ++t) {
            int f = t * 16 + lm;
            if (f < FST) {
                float b = bias ? bias[f] : 0.0f;
#pragma unroll
                for (int r = 0; r < 4; ++r) {
                    float v = acc[t][r] + b;
                    v = (ACT == 1) ? tanhf(v) : fmaxf(v, 0.0f);
                    out[(m0 + q * 4 + r) * (size_t)FST + f] = v;
                }
            }
        }
    } else {
        float* pout = out + (size_t)ks * M * F;
#pragma unroll
        for (int t = 0; t < NT; ++t) {
            int f = t * 16 + lm;
#pragma unroll
            for (int r = 0; r < 4; ++r)
                pout[(m0 + q * 4 + r) * (size_t)F + f] = acc[t][r];
        }
    }
}

// reduce split-K partials: out[m][f<FST] = act(sum_s part[s][m][f] + bias)
template <int KS, int F, int FST, int ACT>
__global__ __launch_bounds__(256)
void k_redact(const float* __restrict__ part, const float* __restrict__ bias,
              float* __restrict__ out, int M) {
    int i = blockIdx.x * 256 + threadIdx.x;
    if (i >= M * FST) return;
    int m = i / FST, f = i - m * FST;
    float v = 0.0f;
#pragma unroll
    for (int s = 0; s < KS; ++s) v += part[((size_t)s * M + m) * F + f];
    if (bias) v += bias[f];
    v = (ACT == 1) ? tanhf(v) : fmaxf(v, 0.0f);
    out[(size_t)m * FST + f] = v;
}

// out[j,f] = max over the 8 fine nodes of group j — emits fp16.
__global__ __launch_bounds__(256)
void k_pool8h(const float* __restrict__ in, _Float16* __restrict__ out, int total, int F) {
    int i = blockIdx.x * 256 + threadIdx.x;
    if (i >= total) return;
    int j = i / F;
    int f = i - j * F;
    const float* p = in + (size_t)(j << 3) * F + f;
    float m = p[0];
#pragma unroll
    for (int r = 1; r < 8; ++r) m = fmaxf(m, p[(size_t)r * F]);
    out[i] = (_Float16)m;
}

extern "C" void kernel_launch(void* const* d_in, const int* in_sizes, int n_in,
                              void* d_out, int out_size, void* d_ws, size_t ws_size,
                              hipStream_t stream) {
    const float* n_feat = (const float*)d_in[0];
    const int* src1 = (const int*)d_in[1];
    const int* dst1 = (const int*)d_in[2];
    const float* pkor1 = (const float*)d_in[3];
    const int* src2 = (const int*)d_in[4];
    const int* dst2 = (const int*)d_in[5];
    const float* pkor2 = (const float*)d_in[6];
    const int* src3 = (const int*)d_in[7];
    const int* dst3 = (const int*)d_in[8];
    const float* pkor3 = (const float*)d_in[9];
    const float* W1 = (const float*)d_in[16];
    const float* mu1 = (const float*)d_in[17];
    const float* is1 = (const float*)d_in[18];
    const float* b1 = (const float*)d_in[19];
    const float* W2 = (const float*)d_in[20];
    const float* mu2 = (const float*)d_in[21];
    const float* is2 = (const float*)d_in[22];
    const float* W3 = (const float*)d_in[23];
    const float* mu3 = (const float*)d_in[24];
    const float* is3 = (const float*)d_in[25];
    const float* W4 = (const float*)d_in[26];
    const float* mu4 = (const float*)d_in[27];
    const float* is4 = (const float*)d_in[28];
    const float* W5 = (const float*)d_in[29];
    const float* mu5 = (const float*)d_in[30];
    const float* is5 = (const float*)d_in[31];
    const float* b5 = (const float*)d_in[32];

    const int E1 = in_sizes[1], E2 = in_sizes[4], E3 = in_sizes[7];
    const int NT_ = N0C + N1C + N2C;

    char* w = (char*)d_ws;
    auto alloc = [&](size_t bytes) {
        void* p = (void*)w;
        w += (bytes + 255) & ~(size_t)255;
        return p;
    };
    int* degs = (int*)alloc((size_t)NT_ * 2 * 4);
    int* deg1 = degs, *deg2 = degs + N0C, *deg3 = degs + N0C + N1C;
    int* cur1 = degs + NT_, *cur2 = cur1 + N0C, *cur3 = cur2 + N1C;
    int* off1 = (int*)alloc(((size_t)N0C + 1) * 4);
    int* off2 = (int*)alloc(((size_t)N1C + 1) * 4);
    int* off3 = (int*)alloc(((size_t)N2C + 1) * 4);
    int* part = (int*)alloc(292 * 4);
    int* csrc1 = (int*)alloc((size_t)E1 * 4);
    float2* cpk1 = (float2*)alloc((size_t)E1 * 8);
    int* csrc2 = (int*)alloc((size_t)E2 * 4);
    float2* cpk2 = (float2*)alloc((size_t)E2 * 8);
    int* csrc3 = (int*)alloc((size_t)E3 * 4);
    float2* cpk3 = (float2*)alloc((size_t)E3 * 8);
    float* inv1 = (float*)alloc((size_t)N0C * 4);
    float* inv2 = (float*)alloc((size_t)N1C * 4);
    float* inv3 = (float*)alloc((size_t)N2C * 4);
    // gw buffers (12 floats per CSR slot): L1|L5|L2|L4|L3
    float* g1 = (float*)alloc(((size_t)2 * E1 + 2 * E2 + E3) * 12 * 4);
    float* g5 = g1 + (size_t)E1 * 12;
    float* g2 = g5 + (size_t)E1 * 12;
    float* g4 = g2 + (size_t)E2 * 12;
    float* g3 = g4 + (size_t)E2 * 12;
    float* out0 = (float*)alloc((size_t)N0C * 32 * 4);
    float* out1 = (float*)alloc((size_t)N1C * 64 * 4);
    float* out2 = (float*)alloc((size_t)N2C * 128 * 4);
    float* out3 = (float*)alloc((size_t)N1C * 64 * 4);
    _Float16* hp1 = (_Float16*)alloc((size_t)N1C * 32 * 2);
    _Float16* hp2 = (_Float16*)alloc((size_t)N2C * 64 * 2);
    _Float16* agg1 = (_Float16*)alloc((size_t)N0C * 32 * 2);
    _Float16* agg2 = (_Float16*)alloc((size_t)N1C * 320 * 2);
    _Float16* agg3 = (_Float16*)alloc((size_t)N2C * 640 * 2);
    _Float16* Wt1 = (_Float16*)alloc((size_t)32 * 32 * 2);
    _Float16* Wt2 = (_Float16*)alloc((size_t)64 * 320 * 2);
    _Float16* Wt3 = (_Float16*)alloc((size_t)128 * 640 * 2);
    _Float16* Wt4 = (_Float16*)alloc((size_t)64 * 1920 * 2);
    _Float16* Wt5 = (_Float16*)alloc((size_t)48 * 960 * 2);
    // tail region: L4 phase = agg4 (31.5MB) + part4 (8.4MB);
    //              L5 phase per chunk = agg5 (chunk*1920B) + part5 (chunk*576B)
    size_t used = (size_t)(w - (char*)d_ws);
    size_t rem = (ws_size > used) ? (ws_size - used) : 0;
    _Float16* agg4 = (_Float16*)w;
    float* part4 = (float*)(w + (((size_t)N1C * 1920 * 2 + 255) & ~(size_t)255));
    int npass = 1;
    while ((size_t)(N0C / npass) * 2496 > rem && npass < 16) npass <<= 1;
    const int chunk = N0C / npass;
    _Float16* agg5 = (_Float16*)w;
    float* part5 = (float*)(w + (((size_t)chunk * 960 * 2 + 255) & ~(size_t)255));

    const int ET = E1 + E2 + E3;
    const int GT = 2 * E1 + 2 * E2 + E3;

    // ---- CSR build (batched) + weight prep + gw precompute
    hipMemsetAsync(degs, 0, (size_t)NT_ * 2 * 4, stream);
    k_prep_wt<<<cdiv(272384, 256), 256, 0, stream>>>(W1, W2, W3, W4, W5,
                                                     Wt1, Wt2, Wt3, Wt4, Wt5);
    k_hist3<<<cdiv(ET, 256), 256, 0, stream>>>(dst1, dst2, dst3, deg1, deg2, deg3, E1, E2, E3);
    k_scan1_3<<<292, 256, 0, stream>>>(deg1, off1, deg2, off2, deg3, off3, part);
    k_scan2_3<<<3, 256, 0, stream>>>(part);
    k_scan3_3<<<292, 256, 0, stream>>>(off1, off2, off3, part, deg1, deg2, deg3,
                                       inv1, inv2, inv3, E1, E2, E3);
    k_scatter3<<<cdiv(ET, 256), 256, 0, stream>>>(
        src1, dst1, pkor1, off1, cur1, csrc1, cpk1,
        src2, dst2, pkor2, off2, cur2, csrc2, cpk2,
        src3, dst3, pkor3, off3, cur3, csrc3, cpk3, E1, E2, E3);
    k_gw<<<cdiv(GT, 256), 256, 0, stream>>>(
        cpk1, cpk2, cpk3, mu1, is1, mu5, is5, mu2, is2, mu4, is4, mu3, is3,
        g1, g5, g2, g4, g3, E1, E2, E3);

    // ---- L1: aggX (Cin=2) -> agg1; GEMM+b1+relu -> out0 (N0,32)
    k_aggx1<<<N0C / 256, 256, 0, stream>>>(n_feat, off1, csrc1, g1, inv1, agg1);
    k_gemm2<4, 2, 1, 1, 0, 32><<<dim3(1, N0C / 64), 256, 0, stream>>>(agg1, Wt1, b1, out0, N0C);

    // ---- L2: pool -> aggX (Cin=32) -> agg2; GEMM+relu -> out1 (N1,64)
    k_pool8h<<<cdiv(N1C * 32, 256), 256, 0, stream>>>(out0, hp1, N1C * 32, 32);
    k_aggx<8><<<cdiv(N1C, 32), 256, 0, stream>>>(hp1, off2, csrc2, g2, inv2, agg2, N1C);
    k_gemm2<2, 4, 10, 1, 0, 64><<<dim3(1, N1C / 32), 128, 0, stream>>>(agg2, Wt2, nullptr, out1, N1C);

    // ---- L3: pool -> aggX (Cin=64) -> agg3; GEMM+relu -> out2 (N2,128)
    k_pool8h<<<cdiv(N2C * 64, 256), 256, 0, stream>>>(out1, hp2, N2C * 64, 64);
    k_aggx<16><<<cdiv(N2C, 16), 256, 0, stream>>>(hp2, off3, csrc3, g3, inv3, agg3, N2C);
    k_gemm2<1, 8, 20, 1, 0, 128><<<dim3(1, N2C / 16), 64, 0, stream>>>(agg3, Wt3, nullptr, out2, N2C);

    // ---- L4: aggF -> agg4; split-K GEMM (KS=4) -> part4; reduce+relu -> out3
    k_aggf<128, 64, 24, 16><<<N1C / 16, 384, 0, stream>>>(
        out2, out1, off2, csrc2, g4, inv2, agg4, 0);
    k_gemm2<2, 4, 15, 4, 0, 64><<<dim3(4, N1C / 32), 128, 0, stream>>>(agg4, Wt4, nullptr, part4, N1C);
    k_redact<4, 64, 64, 0><<<cdiv(N1C * 64, 256), 256, 0, stream>>>(part4, nullptr, out3, N1C);

    // ---- L5: aggF -> agg5 (chunked); split-K GEMM (KS=3) -> part5;
    //      reduce+b5+tanh -> d_out
    for (int p = 0; p < npass; ++p) {
        int base = p * chunk;
        k_aggf<64, 32, 12, 32><<<chunk / 32, 384, 0, stream>>>(
            out3, out0, off1, csrc1, g5, inv1, agg5, base);
        k_gemm2<4, 3, 10, 3, 0, 48><<<dim3(3, chunk / 64), 256, 0, stream>>>(agg5, Wt5, nullptr, part5, chunk);
        k_redact<3, 48, 40, 1><<<cdiv(chunk * 40, 256), 256, 0, stream>>>(
            part5, b5, ((float*)d_out) + (size_t)base * 40, chunk);
    }
}

// Round 10
// 382.044 us; speedup vs baseline: 1.2127x; 1.0806x over previous
//
#include <hip/hip_runtime.h>

// ---------------------------------------------------------------------------
// UNet_old (graph U-Net, GMMConv K=10) on MI355X. fp32 in / fp32 out.
// R10: coalesced fragment-tile GEMM operands. R9 post-mortem: the GEMM's
// A/B loads (lane = row, stride = K-pitch) split into 16 transactions per
// instruction -> ~1 TB/s effective, MfmaUtil 3.6%, immune to wave count.
// All GEMM inputs now stored in MFMA A/B-fragment tile order
// (16x32 tile = 1024B, lane-ordered): aggregation kernels write the
// permuted layout directly, k_prep_wt emits Wt likewise, and every GEMM
// load is 64 lanes x 16B contiguous. Everything else identical to R9.
// ---------------------------------------------------------------------------

#define N0C 65536
#define N1C 8192
#define N2C 1024
#define KK 10

typedef _Float16 half4 __attribute__((ext_vector_type(4)));
typedef _Float16 f16x8 __attribute__((ext_vector_type(8)));
typedef float f32x4 __attribute__((ext_vector_type(4)));

static inline int cdiv(long long a, long long b) { return (int)((a + b - 1) / b); }

// fragment-tile index (in f16x8 units) for matrix row r, k-index kd:
// tile = (r>>4, kd>>5); lane = ((kd>>3)&3)*16 + (r&15); element = kd&7.
__device__ __forceinline__ size_t fragi(int r, int kd, int KDT) {
    return ((size_t)(r >> 4) * KDT + (kd >> 5)) * 64 + ((kd >> 3) & 3) * 16 + (r & 15);
}

// ---------------- batched CSR build (3 graphs) ----------------

__global__ __launch_bounds__(256)
void k_hist3(const int* __restrict__ d1, const int* __restrict__ d2,
             const int* __restrict__ d3, int* __restrict__ g1,
             int* __restrict__ g2, int* __restrict__ g3,
             int E1, int E2, int E3) {
    int i = blockIdx.x * 256 + threadIdx.x;
    if (i < E1) atomicAdd(&g1[d1[i]], 1);
    else if (i < E1 + E2) atomicAdd(&g2[d2[i - E1]], 1);
    else if (i < E1 + E2 + E3) atomicAdd(&g3[d3[i - E1 - E2]], 1);
}

__device__ __forceinline__ void map_graph(int b, int& lb, int& gi) {
    if (b < 256) { gi = 0; lb = b; }
    else if (b < 288) { gi = 1; lb = b - 256; }
    else { gi = 2; lb = b - 288; }
}

__global__ __launch_bounds__(256)
void k_scan1_3(const int* __restrict__ deg1, int* __restrict__ off1,
               const int* __restrict__ deg2, int* __restrict__ off2,
               const int* __restrict__ deg3, int* __restrict__ off3,
               int* __restrict__ part) {
    __shared__ int s[256];
    int lb, gi; map_graph(blockIdx.x, lb, gi);
    const int* deg = gi == 0 ? deg1 : (gi == 1 ? deg2 : deg3);
    int* off = gi == 0 ? off1 : (gi == 1 ? off2 : off3);
    int* prt = part + (gi == 0 ? 0 : (gi == 1 ? 256 : 288));
    int i = lb * 256 + threadIdx.x;
    int v = deg[i];
    s[threadIdx.x] = v;
    __syncthreads();
#pragma unroll
    for (int d = 1; d < 256; d <<= 1) {
        int t = (threadIdx.x >= d) ? s[threadIdx.x - d] : 0;
        __syncthreads();
        s[threadIdx.x] += t;
        __syncthreads();
    }
    off[i] = s[threadIdx.x] - v;
    if (threadIdx.x == 255) prt[lb] = s[255];
}

__global__ __launch_bounds__(256)
void k_scan2_3(int* __restrict__ part) {
    __shared__ int s[256];
    int nb = blockIdx.x == 0 ? 256 : (blockIdx.x == 1 ? 32 : 4);
    int* p = part + (blockIdx.x == 0 ? 0 : (blockIdx.x == 1 ? 256 : 288));
    int v = (threadIdx.x < nb) ? p[threadIdx.x] : 0;
    s[threadIdx.x] = v;
    __syncthreads();
#pragma unroll
    for (int d = 1; d < 256; d <<= 1) {
        int t = (threadIdx.x >= d) ? s[threadIdx.x - d] : 0;
        __syncthreads();
        s[threadIdx.x] += t;
        __syncthreads();
    }
    if (threadIdx.x < nb) p[threadIdx.x] = s[threadIdx.x] - v;
}

__global__ __launch_bounds__(256)
void k_scan3_3(int* __restrict__ off1, int* __restrict__ off2, int* __restrict__ off3,
               const int* __restrict__ part,
               const int* __restrict__ deg1, const int* __restrict__ deg2,
               const int* __restrict__ deg3,
               float* __restrict__ inv1, float* __restrict__ inv2,
               float* __restrict__ inv3, int E1, int E2, int E3) {
    int lb, gi; map_graph(blockIdx.x, lb, gi);
    int* off = gi == 0 ? off1 : (gi == 1 ? off2 : off3);
    const int* deg = gi == 0 ? deg1 : (gi == 1 ? deg2 : deg3);
    float* inv = gi == 0 ? inv1 : (gi == 1 ? inv2 : inv3);
    const int* prt = part + (gi == 0 ? 0 : (gi == 1 ? 256 : 288));
    int n = gi == 0 ? N0C : (gi == 1 ? N1C : N2C);
    int E = gi == 0 ? E1 : (gi == 1 ? E2 : E3);
    int i = lb * 256 + threadIdx.x;
    off[i] += prt[lb];
    inv[i] = 1.0f / fmaxf((float)deg[i], 1.0f);
    if (i == n - 1) off[n] = E;
}

__global__ __launch_bounds__(256)
void k_scatter3(const int* __restrict__ s1, const int* __restrict__ d1,
                const float* __restrict__ p1, const int* __restrict__ o1,
                int* __restrict__ c1, int* __restrict__ cs1, float2* __restrict__ cp1,
                const int* __restrict__ s2, const int* __restrict__ d2,
                const float* __restrict__ p2, const int* __restrict__ o2,
                int* __restrict__ c2, int* __restrict__ cs2, float2* __restrict__ cp2,
                const int* __restrict__ s3, const int* __restrict__ d3,
                const float* __restrict__ p3, const int* __restrict__ o3,
                int* __restrict__ c3, int* __restrict__ cs3, float2* __restrict__ cp3,
                int E1, int E2, int E3) {
    int i = blockIdx.x * 256 + threadIdx.x;
    const int* src; const int* dst; const float* pk; const int* off;
    int* cur; int* csrc; float2* cpk; int e;
    if (i < E1) { src = s1; dst = d1; pk = p1; off = o1; cur = c1; csrc = cs1; cpk = cp1; e = i; }
    else if (i < E1 + E2) { src = s2; dst = d2; pk = p2; off = o2; cur = c2; csrc = cs2; cpk = cp2; e = i - E1; }
    else if (i < E1 + E2 + E3) { src = s3; dst = d3; pk = p3; off = o3; cur = c3; csrc = cs3; cpk = cp3; e = i - E1 - E2; }
    else return;
    int d = dst[e];
    int p = off[d] + atomicAdd(&cur[d], 1);
    csrc[p] = src[e];
    cpk[p] = reinterpret_cast<const float2*>(pk)[e];
}

// ---------------- batched gw precompute (5 layer-graph pairs) --------------
__global__ __launch_bounds__(256)
void k_gw(const float2* __restrict__ cp1, const float2* __restrict__ cp2,
          const float2* __restrict__ cp3,
          const float* __restrict__ mu1, const float* __restrict__ is1,
          const float* __restrict__ mu5, const float* __restrict__ is5,
          const float* __restrict__ mu2, const float* __restrict__ is2,
          const float* __restrict__ mu4, const float* __restrict__ is4,
          const float* __restrict__ mu3, const float* __restrict__ is3,
          float* __restrict__ g1, float* __restrict__ g5, float* __restrict__ g2,
          float* __restrict__ g4, float* __restrict__ g3,
          int E1, int E2, int E3) {
    int i = blockIdx.x * 256 + threadIdx.x;
    const float2* cp; const float* mu; const float* isg; float* g; int e;
    if (i < E1) { cp = cp1; mu = mu1; isg = is1; g = g1; e = i; }
    else if (i < 2 * E1) { cp = cp1; mu = mu5; isg = is5; g = g5; e = i - E1; }
    else if (i < 2 * E1 + E2) { cp = cp2; mu = mu2; isg = is2; g = g2; e = i - 2 * E1; }
    else if (i < 2 * E1 + 2 * E2) { cp = cp2; mu = mu4; isg = is4; g = g4; e = i - 2 * E1 - E2; }
    else if (i < 2 * E1 + 2 * E2 + E3) { cp = cp3; mu = mu3; isg = is3; g = g3; e = i - 2 * E1 - 2 * E2; }
    else return;
    float2 pk = cp[e];
    float o[KK];
#pragma unroll
    for (int k = 0; k < KK; ++k) {
        float dx = (pk.x - mu[2 * k]) * isg[2 * k];
        float dy = (pk.y - mu[2 * k + 1]) * isg[2 * k + 1];
        o[k] = __expf(-0.5f * (dx * dx + dy * dy));
    }
    float4* gp = reinterpret_cast<float4*>(g + (size_t)e * 12);
    gp[0] = make_float4(o[0], o[1], o[2], o[3]);
    gp[1] = make_float4(o[4], o[5], o[6], o[7]);
    gp[2] = make_float4(o[8], o[9], 0.f, 0.f);
}

#define LOAD_G(gw, j, G)                                                     \
    float G[KK];                                                             \
    {                                                                        \
        const float4* gp_ = reinterpret_cast<const float4*>((gw) + (size_t)(j) * 12); \
        float4 g0_ = gp_[0], g1_ = gp_[1]; float2 g2_ = *reinterpret_cast<const float2*>(gp_ + 2); \
        G[0] = g0_.x; G[1] = g0_.y; G[2] = g0_.z; G[3] = g0_.w;              \
        G[4] = g1_.x; G[5] = g1_.y; G[6] = g1_.z; G[7] = g1_.w;              \
        G[8] = g2_.x; G[9] = g2_.y;                                          \
    }

// ---------------- batched weight prep -> B-fragment tiles ----------------
// logical Wt[f][kc] = W[c][k*F+f]; stored at fragi(f, kc, KDT).
__global__ __launch_bounds__(256)
void k_prep_wt(const float* __restrict__ W1, const float* __restrict__ W2,
               const float* __restrict__ W3, const float* __restrict__ W4,
               const float* __restrict__ W5,
               _Float16* __restrict__ T1, _Float16* __restrict__ T2,
               _Float16* __restrict__ T3, _Float16* __restrict__ T4,
               _Float16* __restrict__ T5) {
    int id = blockIdx.x * 256 + threadIdx.x;
    if (id < 1024) {                       // Wt1: F=32, KD=32 (Cin=2, pad 20->32)
        int f = id / 32, kc = id % 32;
        float v = (kc < 20) ? W1[(kc % 2) * 320 + (kc / 2) * 32 + f] : 0.0f;
        T1[fragi(f, kc, 1) * 8 + (kc & 7)] = (_Float16)v;
        return;
    }
    id -= 1024;
    if (id < 20480) {                      // Wt2: F=64, KD=320 (Cin=32)
        int f = id / 320, kc = id % 320;
        T2[fragi(f, kc, 10) * 8 + (kc & 7)] = (_Float16)W2[(kc % 32) * 640 + (kc / 32) * 64 + f];
        return;
    }
    id -= 20480;
    if (id < 81920) {                      // Wt3: F=128, KD=640 (Cin=64)
        int f = id / 640, kc = id % 640;
        T3[fragi(f, kc, 20) * 8 + (kc & 7)] = (_Float16)W3[(kc % 64) * 1280 + (kc / 64) * 128 + f];
        return;
    }
    id -= 81920;
    if (id < 122880) {                     // Wt4: F=64, KD=1920 (Cin=192)
        int f = id / 1920, kc = id % 1920;
        T4[fragi(f, kc, 60) * 8 + (kc & 7)] = (_Float16)W4[(kc % 192) * 640 + (kc / 192) * 64 + f];
        return;
    }
    id -= 122880;
    if (id < 46080) {                      // Wt5: F=48 (store 40), KD=960 (Cin=96)
        int f = id / 960, kc = id % 960;
        float v = (f < 40) ? W5[(kc % 96) * 400 + (kc / 96) * 40 + f] : 0.0f;
        T5[fragi(f, kc, 30) * 8 + (kc & 7)] = (_Float16)v;
    }
}

// ---------------- L1 aggregate-X (Cin=2): 1 thread/node, frag output ------
__global__ __launch_bounds__(256, 4)
void k_aggx1(const float* __restrict__ x, const int* __restrict__ off,
             const int* __restrict__ csrc, const float* __restrict__ gw,
             const float* __restrict__ inv, _Float16* __restrict__ agg) {
    int n = blockIdx.x * 256 + threadIdx.x;
    if (n >= N0C) return;
    float a0[KK], a1[KK];
#pragma unroll
    for (int k = 0; k < KK; ++k) { a0[k] = 0.f; a1[k] = 0.f; }
    int j0 = off[n], j1 = off[n + 1];
    for (int j = j0; j < j1; ++j) {
        int s = csrc[j];
        LOAD_G(gw, j, G)
        float2 xv = reinterpret_cast<const float2*>(x)[s];
#pragma unroll
        for (int k = 0; k < KK; ++k) {
            a0[k] = fmaf(G[k], xv.x, a0[k]);
            a1[k] = fmaf(G[k], xv.y, a1[k]);
        }
    }
    float iv = inv[n];
    f16x8* out = reinterpret_cast<f16x8*>(agg);
    const size_t base = (size_t)(n >> 4) * 64 + (n & 15);
#pragma unroll
    for (int u = 0; u < 4; ++u) {
        f16x8 v;
#pragma unroll
        for (int e = 0; e < 8; ++e) {
            int kc = u * 8 + e;
            float val = (kc < 20) ? ((kc & 1) ? a1[kc >> 1] : a0[kc >> 1]) * iv : 0.f;
            v[e] = (_Float16)val;
        }
        out[base + u * 16] = v;   // KDT=1, jt=0, q=u
    }
}

// ---------------- split aggregate-X (fp16 node-major src) for L2/L3 -------
// frag output: kd = k*CIN + 4*tt (4-aligned -> 8B sub-store).
template <int TPN>
__global__ __launch_bounds__(256, 4)
void k_aggx(const _Float16* __restrict__ xp, const int* __restrict__ off,
            const int* __restrict__ csrc, const float* __restrict__ gw,
            const float* __restrict__ inv, _Float16* __restrict__ agg, int N) {
    constexpr int CIN = TPN * 4;
    constexpr int KDT = KK * CIN / 32;
    int tid = threadIdx.x;
    int nl = tid / TPN, tt = tid - nl * TPN;
    int node = blockIdx.x * (256 / TPN) + nl;
    if (node >= N) return;
    float a[KK][4];
#pragma unroll
    for (int k = 0; k < KK; ++k)
#pragma unroll
        for (int e = 0; e < 4; ++e) a[k][e] = 0.f;
    int j0 = off[node], j1 = off[node + 1];
    for (int j = j0; j < j1; ++j) {
        int s = csrc[j];
        LOAD_G(gw, j, G)
        half4 hv = *reinterpret_cast<const half4*>(xp + (size_t)s * CIN + 4 * tt);
        float x0 = hv[0], x1 = hv[1], x2 = hv[2], x3 = hv[3];
#pragma unroll
        for (int k = 0; k < KK; ++k) {
            a[k][0] = fmaf(G[k], x0, a[k][0]);
            a[k][1] = fmaf(G[k], x1, a[k][1]);
            a[k][2] = fmaf(G[k], x2, a[k][2]);
            a[k][3] = fmaf(G[k], x3, a[k][3]);
        }
    }
    float iv = inv[node];
#pragma unroll
    for (int k = 0; k < KK; ++k) {
        half4 o;
        o[0] = (_Float16)(a[k][0] * iv); o[1] = (_Float16)(a[k][1] * iv);
        o[2] = (_Float16)(a[k][2] * iv); o[3] = (_Float16)(a[k][3] * iv);
        int kd = k * CIN + 4 * tt;
        *reinterpret_cast<half4*>(agg + fragi(node, kd, KDT) * 8 + (kd & 7)) = o;
    }
}

// ---------------- L4/L5 aggregate (fp32 concat src) -> frag output --------
template <int CA, int CB, int TPN, int NPB>
__global__ __launch_bounds__(TPN * NPB, 3)
void k_aggf(const float* __restrict__ xA, const float* __restrict__ xB,
            const int* __restrict__ off, const int* __restrict__ csrc,
            const float* __restrict__ gw, const float* __restrict__ inv,
            _Float16* __restrict__ agg, int nodeBase) {
    constexpr int CIN = CA + CB;
    constexpr int KDT = KK * CIN / 32;
    const int tid = threadIdx.x;
    int nl = tid / TPN, tt = tid - nl * TPN;
    int lnode = blockIdx.x * NPB + nl;
    int node = nodeBase + lnode;
    int c0 = 8 * tt;
    float a[KK][8];
#pragma unroll
    for (int k = 0; k < KK; ++k)
#pragma unroll
        for (int e = 0; e < 8; ++e) a[k][e] = 0.f;
    int j0 = off[node], j1 = off[node + 1];
    for (int j = j0; j < j1; ++j) {
        int s = csrc[j];
        LOAD_G(gw, j, G)
        const float* bsrc = (c0 < CA) ? (xA + (size_t)(s >> 3) * CA + c0)
                                      : (xB + (size_t)s * CB + (c0 - CA));
        float4 xa = reinterpret_cast<const float4*>(bsrc)[0];
        float4 xb = reinterpret_cast<const float4*>(bsrc)[1];
#pragma unroll
        for (int k = 0; k < KK; ++k) {
            a[k][0] = fmaf(G[k], xa.x, a[k][0]);
            a[k][1] = fmaf(G[k], xa.y, a[k][1]);
            a[k][2] = fmaf(G[k], xa.z, a[k][2]);
            a[k][3] = fmaf(G[k], xa.w, a[k][3]);
            a[k][4] = fmaf(G[k], xb.x, a[k][4]);
            a[k][5] = fmaf(G[k], xb.y, a[k][5]);
            a[k][6] = fmaf(G[k], xb.z, a[k][6]);
            a[k][7] = fmaf(G[k], xb.w, a[k][7]);
        }
    }
    float iv = inv[node];
    f16x8* out = reinterpret_cast<f16x8*>(agg);
#pragma unroll
    for (int k = 0; k < KK; ++k) {
        f16x8 v;
#pragma unroll
        for (int e = 0; e < 8; ++e) v[e] = (_Float16)(a[k][e] * iv);
        out[fragi(lnode, k * CIN + c0, KDT)] = v;
    }
}

// ---------------- pipelined split-K MFMA GEMM (fragment-tile operands) -----
// A: [mblk][kt][lane] f16x8 tiles; B: [nblk][kt][lane]. KD = KS*ITERS*32.
template <int WB, int NT, int ITERS, int KS, int ACT, int FST>
__global__ __launch_bounds__(WB * 64)
void k_gemm2(const _Float16* __restrict__ A, const _Float16* __restrict__ B,
             const float* __restrict__ bias, float* __restrict__ out, int M) {
    constexpr int KDT = KS * ITERS;
    constexpr int F = NT * 16;
    const int lane = threadIdx.x & 63;
    const int wv = threadIdx.x >> 6;
    const int lm = lane & 15;
    const int q = lane >> 4;
    const int ks = blockIdx.x;
    const int t0 = ks * ITERS;
    const size_t m0 = (size_t)blockIdx.y * (WB * 16) + wv * 16;
    const size_t mblk = m0 >> 4;
    f32x4 acc[NT];
#pragma unroll
    for (int t = 0; t < NT; ++t) acc[t] = (f32x4){0.f, 0.f, 0.f, 0.f};
    const f16x8* ap = (const f16x8*)A + (mblk * KDT + t0) * 64 + lane;
    const f16x8* bp = (const f16x8*)B + (size_t)t0 * 64 + lane;
    f16x8 af = ap[0];
    f16x8 bf[NT];
#pragma unroll
    for (int t = 0; t < NT; ++t) bf[t] = bp[(size_t)t * KDT * 64];
#pragma unroll
    for (int i = 0; i < ITERS; ++i) {
        f16x8 afn; f16x8 bfn[NT];
        if (i + 1 < ITERS) {
            afn = ap[(size_t)(i + 1) * 64];
#pragma unroll
            for (int t = 0; t < NT; ++t)
                bfn[t] = bp[((size_t)t * KDT + i + 1) * 64];
        }
#pragma unroll
        for (int t = 0; t < NT; ++t)
            acc[t] = __builtin_amdgcn_mfma_f32_16x16x32_f16(af, bf[t], acc[t], 0, 0, 0);
        af = afn;
#pragma unroll
        for (int t = 0; t < NT; ++t) bf[t] = bfn[t];
    }
    if (KS == 1) {
#pragma unroll
        for (int t = 0; t < NT; ++t) {
            int f = t * 16 + lm;
            if (f < FST) {
                float b = bias ? bias[f] : 0.0f;
#pragma unroll
                for (int r = 0; r < 4; ++r) {
                    float v = acc[t][r] + b;
                    v = (ACT == 1) ? tanhf(v) : fmaxf(v, 0.0f);
                    out[(m0 + q * 4 + r) * (size_t)FST + f] = v;
                }
            }
        }
    } else {
        float* pout = out + (size_t)ks * M * F;
#pragma unroll
        for (int t = 0; t < NT; ++t) {
            int f = t * 16 + lm;
#pragma unroll
            for (int r = 0; r < 4; ++r)
                pout[(m0 + q * 4 + r) * (size_t)F + f] = acc[t][r];
        }
    }
}

// reduce split-K partials: out[m][f<FST] = act(sum_s part[s][m][f] + bias)
template <int KS, int F, int FST, int ACT>
__global__ __launch_bounds__(256)
void k_redact(const float* __restrict__ part, const float* __restrict__ bias,
              float* __restrict__ out, int M) {
    int i = blockIdx.x * 256 + threadIdx.x;
    if (i >= M * FST) return;
    int m = i / FST, f = i - m * FST;
    float v = 0.0f;
#pragma unroll
    for (int s = 0; s < KS; ++s) v += part[((size_t)s * M + m) * F + f];
    if (bias) v += bias[f];
    v = (ACT == 1) ? tanhf(v) : fmaxf(v, 0.0f);
    out[(size_t)m * FST + f] = v;
}

// out[j,f] = max over the 8 fine nodes of group j — emits fp16 (node-major).
__global__ __launch_bounds__(256)
void k_pool8h(const float* __restrict__ in, _Float16* __restrict__ out, int total, int F) {
    int i = blockIdx.x * 256 + threadIdx.x;
    if (i >= total) return;
    int j = i / F;
    int f = i - j * F;
    const float* p = in + (size_t)(j << 3) * F + f;
    float m = p[0];
#pragma unroll
    for (int r = 1; r < 8; ++r) m = fmaxf(m, p[(size_t)r * F]);
    out[i] = (_Float16)m;
}

extern "C" void kernel_launch(void* const* d_in, const int* in_sizes, int n_in,
                              void* d_out, int out_size, void* d_ws, size_t ws_size,
                              hipStream_t stream) {
    const float* n_feat = (const float*)d_in[0];
    const int* src1 = (const int*)d_in[1];
    const int* dst1 = (const int*)d_in[2];
    const float* pkor1 = (const float*)d_in[3];
    const int* src2 = (const int*)d_in[4];
    const int* dst2 = (const int*)d_in[5];
    const float* pkor2 = (const float*)d_in[6];
    const int* src3 = (const int*)d_in[7];
    const int* dst3 = (const int*)d_in[8];
    const float* pkor3 = (const float*)d_in[9];
    const float* W1 = (const float*)d_in[16];
    const float* mu1 = (const float*)d_in[17];
    const float* is1 = (const float*)d_in[18];
    const float* b1 = (const float*)d_in[19];
    const float* W2 = (const float*)d_in[20];
    const float* mu2 = (const float*)d_in[21];
    const float* is2 = (const float*)d_in[22];
    const float* W3 = (const float*)d_in[23];
    const float* mu3 = (const float*)d_in[24];
    const float* is3 = (const float*)d_in[25];
    const float* W4 = (const float*)d_in[26];
    const float* mu4 = (const float*)d_in[27];
    const float* is4 = (const float*)d_in[28];
    const float* W5 = (const float*)d_in[29];
    const float* mu5 = (const float*)d_in[30];
    const float* is5 = (const float*)d_in[31];
    const float* b5 = (const float*)d_in[32];

    const int E1 = in_sizes[1], E2 = in_sizes[4], E3 = in_sizes[7];
    const int NT_ = N0C + N1C + N2C;

    char* w = (char*)d_ws;
    auto alloc = [&](size_t bytes) {
        void* p = (void*)w;
        w += (bytes + 255) & ~(size_t)255;
        return p;
    };
    int* degs = (int*)alloc((size_t)NT_ * 2 * 4);
    int* deg1 = degs, *deg2 = degs + N0C, *deg3 = degs + N0C + N1C;
    int* cur1 = degs + NT_, *cur2 = cur1 + N0C, *cur3 = cur2 + N1C;
    int* off1 = (int*)alloc(((size_t)N0C + 1) * 4);
    int* off2 = (int*)alloc(((size_t)N1C + 1) * 4);
    int* off3 = (int*)alloc(((size_t)N2C + 1) * 4);
    int* part = (int*)alloc(292 * 4);
    int* csrc1 = (int*)alloc((size_t)E1 * 4);
    float2* cpk1 = (float2*)alloc((size_t)E1 * 8);
    int* csrc2 = (int*)alloc((size_t)E2 * 4);
    float2* cpk2 = (float2*)alloc((size_t)E2 * 8);
    int* csrc3 = (int*)alloc((size_t)E3 * 4);
    float2* cpk3 = (float2*)alloc((size_t)E3 * 8);
    float* inv1 = (float*)alloc((size_t)N0C * 4);
    float* inv2 = (float*)alloc((size_t)N1C * 4);
    float* inv3 = (float*)alloc((size_t)N2C * 4);
    float* g1 = (float*)alloc(((size_t)2 * E1 + 2 * E2 + E3) * 12 * 4);
    float* g5 = g1 + (size_t)E1 * 12;
    float* g2 = g5 + (size_t)E1 * 12;
    float* g4 = g2 + (size_t)E2 * 12;
    float* g3 = g4 + (size_t)E2 * 12;
    float* out0 = (float*)alloc((size_t)N0C * 32 * 4);
    float* out1 = (float*)alloc((size_t)N1C * 64 * 4);
    float* out2 = (float*)alloc((size_t)N2C * 128 * 4);
    float* out3 = (float*)alloc((size_t)N1C * 64 * 4);
    _Float16* hp1 = (_Float16*)alloc((size_t)N1C * 32 * 2);
    _Float16* hp2 = (_Float16*)alloc((size_t)N2C * 64 * 2);
    _Float16* agg1 = (_Float16*)alloc((size_t)N0C * 32 * 2);
    _Float16* agg2 = (_Float16*)alloc((size_t)N1C * 320 * 2);
    _Float16* agg3 = (_Float16*)alloc((size_t)N2C * 640 * 2);
    _Float16* Wt1 = (_Float16*)alloc((size_t)32 * 32 * 2);
    _Float16* Wt2 = (_Float16*)alloc((size_t)64 * 320 * 2);
    _Float16* Wt3 = (_Float16*)alloc((size_t)128 * 640 * 2);
    _Float16* Wt4 = (_Float16*)alloc((size_t)64 * 1920 * 2);
    _Float16* Wt5 = (_Float16*)alloc((size_t)48 * 960 * 2);
    size_t used = (size_t)(w - (char*)d_ws);
    size_t rem = (ws_size > used) ? (ws_size - used) : 0;
    _Float16* agg4 = (_Float16*)w;
    float* part4 = (float*)(w + (((size_t)N1C * 1920 * 2 + 255) & ~(size_t)255));
    int npass = 1;
    while ((size_t)(N0C / npass) * 2496 > rem && npass < 16) npass <<= 1;
    const int chunk = N0C / npass;
    _Float16* agg5 = (_Float16*)w;
    float* part5 = (float*)(w + (((size_t)chunk * 960 * 2 + 255) & ~(size_t)255));

    const int ET = E1 + E2 + E3;
    const int GT = 2 * E1 + 2 * E2 + E3;

    // ---- CSR build (batched) + weight prep + gw precompute
    hipMemsetAsync(degs, 0, (size_t)NT_ * 2 * 4, stream);
    k_prep_wt<<<cdiv(272384, 256), 256, 0, stream>>>(W1, W2, W3, W4, W5,
                                                     Wt1, Wt2, Wt3, Wt4, Wt5);
    k_hist3<<<cdiv(ET, 256), 256, 0, stream>>>(dst1, dst2, dst3, deg1, deg2, deg3, E1, E2, E3);
    k_scan1_3<<<292, 256, 0, stream>>>(deg1, off1, deg2, off2, deg3, off3, part);
    k_scan2_3<<<3, 256, 0, stream>>>(part);
    k_scan3_3<<<292, 256, 0, stream>>>(off1, off2, off3, part, deg1, deg2, deg3,
                                       inv1, inv2, inv3, E1, E2, E3);
    k_scatter3<<<cdiv(ET, 256), 256, 0, stream>>>(
        src1, dst1, pkor1, off1, cur1, csrc1, cpk1,
        src2, dst2, pkor2, off2, cur2, csrc2, cpk2,
        src3, dst3, pkor3, off3, cur3, csrc3, cpk3, E1, E2, E3);
    k_gw<<<cdiv(GT, 256), 256, 0, stream>>>(
        cpk1, cpk2, cpk3, mu1, is1, mu5, is5, mu2, is2, mu4, is4, mu3, is3,
        g1, g5, g2, g4, g3, E1, E2, E3);

    // ---- L1: aggX (Cin=2) -> agg1 (frag); GEMM+b1+relu -> out0 (N0,32)
    k_aggx1<<<N0C / 256, 256, 0, stream>>>(n_feat, off1, csrc1, g1, inv1, agg1);
    k_gemm2<4, 2, 1, 1, 0, 32><<<dim3(1, N0C / 64), 256, 0, stream>>>(agg1, Wt1, b1, out0, N0C);

    // ---- L2: pool -> aggX (Cin=32) -> agg2 (frag); GEMM+relu -> out1 (N1,64)
    k_pool8h<<<cdiv(N1C * 32, 256), 256, 0, stream>>>(out0, hp1, N1C * 32, 32);
    k_aggx<8><<<cdiv(N1C, 32), 256, 0, stream>>>(hp1, off2, csrc2, g2, inv2, agg2, N1C);
    k_gemm2<2, 4, 10, 1, 0, 64><<<dim3(1, N1C / 32), 128, 0, stream>>>(agg2, Wt2, nullptr, out1, N1C);

    // ---- L3: pool -> aggX (Cin=64) -> agg3 (frag); GEMM+relu -> out2 (N2,128)
    k_pool8h<<<cdiv(N2C * 64, 256), 256, 0, stream>>>(out1, hp2, N2C * 64, 64);
    k_aggx<16><<<cdiv(N2C, 16), 256, 0, stream>>>(hp2, off3, csrc3, g3, inv3, agg3, N2C);
    k_gemm2<1, 8, 20, 1, 0, 128><<<dim3(1, N2C / 16), 64, 0, stream>>>(agg3, Wt3, nullptr, out2, N2C);

    // ---- L4: aggF -> agg4 (frag); split-K GEMM (KS=4) -> part4; reduce+relu
    k_aggf<128, 64, 24, 16><<<N1C / 16, 384, 0, stream>>>(
        out2, out1, off2, csrc2, g4, inv2, agg4, 0);
    k_gemm2<2, 4, 15, 4, 0, 64><<<dim3(4, N1C / 32), 128, 0, stream>>>(agg4, Wt4, nullptr, part4, N1C);
    k_redact<4, 64, 64, 0><<<cdiv(N1C * 64, 256), 256, 0, stream>>>(part4, nullptr, out3, N1C);

    // ---- L5: aggF -> agg5 (frag, chunked); split-K GEMM (KS=3) -> part5;
    //      reduce+b5+tanh -> d_out
    for (int p = 0; p < npass; ++p) {
        int base = p * chunk;
        k_aggf<64, 32, 12, 32><<<chunk / 32, 384, 0, stream>>>(
            out3, out0, off1, csrc1, g5, inv1, agg5, base);
        k_gemm2<4, 3, 10, 3, 0, 48><<<dim3(3, chunk / 64), 256, 0, stream>>>(agg5, Wt5, nullptr, part5, chunk);
        k_redact<3, 48, 40, 1><<<cdiv(chunk * 40, 256), 256, 0, stream>>>(
            part5, b5, ((float*)d_out) + (size_t)base * 40, chunk);
    }
}